// Round 1
// baseline (215.289 us; speedup 1.0000x reference)
//
#include <hip/hip_runtime.h>
#include <stddef.h>

typedef __attribute__((ext_vector_type(8))) short short8;
typedef __attribute__((ext_vector_type(4))) float f32x4;
typedef unsigned short ushort_t;
typedef unsigned int uint_t;

#define NN 128
#define TT 1024
#define CC 256
#define NT 131072.0f   // N*T
#define EPS 1e-5f

__device__ __forceinline__ float bf2f(ushort_t u){
    union { float f; uint_t i; } v; v.i = ((uint_t)u) << 16; return v.f;
}
__device__ __forceinline__ ushort_t f2bf(float f){
    union { float f; uint_t i; } v; v.f = f;
    uint_t r = v.i + 0x7fffu + ((v.i >> 16) & 1u);
    return (ushort_t)(r >> 16);
}
__device__ __forceinline__ void wave_red(float& v){
    #pragma unroll
    for (int off = 32; off > 0; off >>= 1) v += __shfl_down(v, off);
}

// ---------------- Pass 1: per-channel stats of x (two-stage, deterministic) ----
// grid 512, block 256. Block b handles rows [b*256, b*256+256) of the 131072 (n,t) rows.
__global__ __launch_bounds__(256) void k_stats1(const float* __restrict__ x,
                                                float* __restrict__ psum,
                                                float* __restrict__ psq){
    const int b = blockIdx.x, c = threadIdx.x;
    const float* p = x + ((size_t)b << 16) + c;   // b*256 rows * 256 ch
    float s = 0.f, q = 0.f;
    #pragma unroll 4
    for (int r = 0; r < 256; ++r){
        float v = p[(size_t)r * 256];
        s += v; q = fmaf(v, v, q);
    }
    psum[c * 512 + b] = s;
    psq [c * 512 + b] = q;
}

// grid 256 (one per channel), block 256: reduce partials, emit BN1 affine + shift params.
__global__ __launch_bounds__(256) void k_fin1(const float* __restrict__ psum,
                                              const float* __restrict__ psq,
                                              const float* __restrict__ g1,
                                              const float* __restrict__ be1,
                                              const float* __restrict__ sin_,
                                              const float* __restrict__ sout,
                                              float* __restrict__ s1, float* __restrict__ b1,
                                              float* __restrict__ a0i, float* __restrict__ a1i,
                                              int* __restrict__ i1i,
                                              float* __restrict__ a0o, float* __restrict__ a1o,
                                              int* __restrict__ j1o){
    const int c = blockIdx.x, t = threadIdx.x;
    float s = psum[c * 512 + t] + psum[c * 512 + 256 + t];
    float q = psq [c * 512 + t] + psq [c * 512 + 256 + t];
    wave_red(s); wave_red(q);
    __shared__ float sm[8];
    const int wv = t >> 6, ln = t & 63;
    if (ln == 0){ sm[wv] = s; sm[4 + wv] = q; }
    __syncthreads();
    if (t == 0){
        float S = sm[0] + sm[1] + sm[2] + sm[3];
        float Q = sm[4] + sm[5] + sm[6] + sm[7];
        float mean = S / NT;
        float var  = Q / NT - mean * mean;
        float rstd = rsqrtf(var + EPS);
        float sc = rstd * g1[c];
        s1[c] = sc;
        b1[c] = be1[c] - mean * sc;
        float sv = sin_[c]; float fi = floorf(sv); float fr = sv - fi;
        a0i[c] = 1.f - fr; a1i[c] = fr; i1i[c] = (int)fi + 1;
        float so = sout[c]; float fo = floorf(so); float fro = so - fo;
        a0o[c] = 1.f - fro; a1o[c] = fro; j1o[c] = (int)fo + 1;
    }
}

// ---------------- W -> bf16 fragment-major layout ------------------------------
// WF[((ks*16 + ob)*64 + lane)*8 + j] = bf16( W[(ob*16 + (lane&15))*256 + ks*32 + (lane>>4)*8 + j] )
__global__ __launch_bounds__(256) void k_wf(const float* __restrict__ W, ushort_t* __restrict__ WF){
    const int gid = blockIdx.x * 256 + threadIdx.x;   // 8192 threads
    const int l = gid & 63, ob = (gid >> 6) & 15, ks = gid >> 10;
    const int row = ob * 16 + (l & 15);
    const int k0  = ks * 32 + (l >> 4) * 8;
    #pragma unroll
    for (int j = 0; j < 8; ++j)
        WF[(size_t)gid * 8 + j] = f2bf(W[(size_t)row * 256 + k0 + j]);
}

// ---------------- Pass 2: fused BN1 + shift_in + conv + bias + relu -> Y bf16 (n,t,o)
// grid 2048 = (n, t-tile of 64), block 256 (4 waves). LDS 33 KB.
__global__ __launch_bounds__(256) void k_conv(const float* __restrict__ x,
                                              const ushort_t* __restrict__ WF,
                                              const float* __restrict__ cb,
                                              const float* __restrict__ s1,
                                              const float* __restrict__ b1,
                                              const float* __restrict__ a0i,
                                              const float* __restrict__ a1i,
                                              const int* __restrict__ i1i,
                                              ushort_t* __restrict__ Y){
    __shared__ __align__(16) ushort_t lds[16512];   // 64*256 Xs / 64*258 out-tile
    const int tid = threadIdx.x;
    const int n  = blockIdx.x >> 4;
    const int t0 = (blockIdx.x & 15) << 6;

    // ---- build shifted, BN1'd bf16 tile Xs[t_local][c] (XOR-swizzled) ----
    {
        const int c = tid;
        const float s1c = s1[c], b1c = b1[c], a0c = a0i[c], a1c = a1i[c];
        const int i1c = i1i[c];
        const float* xb_base = x + ((size_t)n << 18) + c;
        float xb_prev = 0.f;
        #pragma unroll 4
        for (int u = -1; u <= 64; ++u){
            const int g = t0 + u;
            float xb = 0.f;
            if (g >= 0 && g < TT) xb = fmaf(xb_base[(size_t)g * 256], s1c, b1c);
            const int tw = u - i1c;
            if (tw >= 0 && tw < 64){
                float v = a0c * xb_prev + a1c * xb;
                lds[(tw << 8) + (c ^ ((tw & 7) << 3))] = f2bf(v);
            }
            xb_prev = xb;
        }
    }
    __syncthreads();

    // ---- MFMA: out tile 256(o) x 64(t), wave wv owns o in [wv*64, wv*64+64) ----
    const int wv = tid >> 6, ln = tid & 63;
    const int l15 = ln & 15, lg = ln >> 4;
    f32x4 acc[4][4];
    #pragma unroll
    for (int r = 0; r < 4; ++r)
        #pragma unroll
        for (int q = 0; q < 4; ++q)
            acc[r][q] = (f32x4){0.f, 0.f, 0.f, 0.f};

    const short8* wf8 = (const short8*)WF;
    #pragma unroll
    for (int ks = 0; ks < 8; ++ks){
        short8 aF[4], bF[4];
        #pragma unroll
        for (int r = 0; r < 4; ++r)
            aF[r] = wf8[(ks * 16 + wv * 4 + r) * 64 + ln];
        const int kk = (ks << 5) + (lg << 3);
        #pragma unroll
        for (int q = 0; q < 4; ++q){
            const int t = (q << 4) | l15;
            bF[q] = *(const short8*)&lds[(t << 8) + (kk ^ ((t & 7) << 3))];
        }
        #pragma unroll
        for (int r = 0; r < 4; ++r)
            #pragma unroll
            for (int q = 0; q < 4; ++q)
                acc[r][q] = __builtin_amdgcn_mfma_f32_16x16x32_bf16(aF[r], bF[q], acc[r][q], 0, 0, 0);
    }
    __syncthreads();

    // ---- epilogue: bias + relu, transpose to [t][o] in LDS (stride 258) ----
    float cbv[4][4];
    #pragma unroll
    for (int r = 0; r < 4; ++r)
        #pragma unroll
        for (int j = 0; j < 4; ++j)
            cbv[r][j] = cb[(wv << 6) + (r << 4) + (lg << 2) + j];
    #pragma unroll
    for (int r = 0; r < 4; ++r)
        #pragma unroll
        for (int q = 0; q < 4; ++q)
            #pragma unroll
            for (int j = 0; j < 4; ++j){
                const int o = (wv << 6) + (r << 4) + (lg << 2) + j;
                const int t = (q << 4) | l15;
                float v = acc[r][q][j] + cbv[r][j];
                v = v > 0.f ? v : 0.f;
                lds[t * 258 + o] = f2bf(v);
            }
    __syncthreads();

    // ---- coalesced store: Y[(n*1024 + t0 + t)*256 + o], 2 bf16 per thread ----
    uint_t* Yu = (uint_t*)Y;
    const size_t rbase = ((size_t)n << 10) + t0;
    #pragma unroll
    for (int it = 0; it < 32; ++it){
        const int idx = it * 256 + tid;
        const int row = idx >> 7, col = idx & 127;
        const uint_t v = *(const uint_t*)&lds[row * 258 + col * 2];
        Yu[((rbase + row) << 7) + col] = v;
    }
}

// ---------------- Pass 3a: stats of shifted Y (P, Q, R, boundary terms) --------
// grid 512 = (n, quarter of T), block 256 (thread = o).
__global__ __launch_bounds__(256) void k_zstats(const ushort_t* __restrict__ Y,
                                                float* __restrict__ ZP, float* __restrict__ ZQ,
                                                float* __restrict__ ZR,
                                                float* __restrict__ B0p, float* __restrict__ B0q,
                                                float* __restrict__ BTp, float* __restrict__ BTq){
    const int b = blockIdx.x;
    const int n = b >> 2, t0 = (b & 3) << 8, o = threadIdx.x;
    const ushort_t* yp = Y + (((size_t)n << 10) << 8) + o;
    float P = 0.f, Q = 0.f, R = 0.f;
    float prev = (t0 > 0) ? bf2f(yp[(size_t)(t0 - 1) * 256]) : 0.f;
    #pragma unroll 4
    for (int t = t0; t < t0 + 256; ++t){
        float y = bf2f(yp[(size_t)t * 256]);
        P += y; Q = fmaf(y, y, Q);
        if (t > 0) R = fmaf(prev, y, R);
        prev = y;
    }
    ZP[o * 512 + b] = P; ZQ[o * 512 + b] = Q; ZR[o * 512 + b] = R;
    if (t0 == 0){
        float y0 = bf2f(yp[0]);
        B0p[o * 128 + n] = y0; B0q[o * 128 + n] = y0 * y0;
    }
    if (t0 == 768){
        float yT = bf2f(yp[(size_t)1023 * 256]);
        BTp[o * 128 + n] = yT; BTq[o * 128 + n] = yT * yT;
    }
}

// grid 256 (one per o), block 256: reduce + assemble shifted stats -> BN2 affine.
__global__ __launch_bounds__(256) void k_fin2(const float* __restrict__ ZP,
                                              const float* __restrict__ ZQ,
                                              const float* __restrict__ ZR,
                                              const float* __restrict__ B0p,
                                              const float* __restrict__ B0q,
                                              const float* __restrict__ BTp,
                                              const float* __restrict__ BTq,
                                              const float* __restrict__ g2,
                                              const float* __restrict__ be2,
                                              const float* __restrict__ a0o,
                                              const float* __restrict__ a1o,
                                              const int* __restrict__ j1o,
                                              float* __restrict__ s2, float* __restrict__ b2){
    const int o = blockIdx.x, t = threadIdx.x;
    float P = ZP[o * 512 + t] + ZP[o * 512 + 256 + t];
    float Q = ZQ[o * 512 + t] + ZQ[o * 512 + 256 + t];
    float R = ZR[o * 512 + t] + ZR[o * 512 + 256 + t];
    float b0 = 0.f, b0s = 0.f, btv = 0.f, bts = 0.f;
    if (t < 128){
        b0 = B0p[o * 128 + t]; b0s = B0q[o * 128 + t];
        btv = BTp[o * 128 + t]; bts = BTq[o * 128 + t];
    }
    wave_red(P); wave_red(Q); wave_red(R);
    wave_red(b0); wave_red(b0s); wave_red(btv); wave_red(bts);
    __shared__ float sm[4][7];
    const int wv = t >> 6, ln = t & 63;
    if (ln == 0){
        sm[wv][0] = P; sm[wv][1] = Q; sm[wv][2] = R;
        sm[wv][3] = b0; sm[wv][4] = b0s; sm[wv][5] = btv; sm[wv][6] = bts;
    }
    __syncthreads();
    if (t == 0){
        float v[7];
        #pragma unroll
        for (int k = 0; k < 7; ++k)
            v[k] = sm[0][k] + sm[1][k] + sm[2][k] + sm[3][k];
        const float a0 = a0o[o], a1 = a1o[o];
        const int j1 = j1o[o];
        float sz, sq;
        if (j1 == 0){   // i0 = -1 : Z[t] = a0*Y[t-1](t>=1) + a1*Y[t]
            sz = a0 * (v[0] - v[5]) + a1 * v[0];
            sq = a0 * a0 * (v[1] - v[6]) + a1 * a1 * v[1] + 2.f * a0 * a1 * v[2];
        } else {        // i0 = 0 : Z[t] = a0*Y[t] + a1*Y[t+1](t<=T-2)
            sz = a0 * v[0] + a1 * (v[0] - v[3]);
            sq = a0 * a0 * v[1] + a1 * a1 * (v[1] - v[4]) + 2.f * a0 * a1 * v[2];
        }
        float mean = sz / NT;
        float var  = sq / NT - mean * mean;
        float rstd = rsqrtf(var + EPS);
        float sc = rstd * g2[o];
        s2[o] = sc;
        b2[o] = be2[o] - mean * sc;
    }
}

// ---------------- Pass 3b: shift_out + BN2 + write fp32 output (n,t,o) ---------
// grid 512 = (n, quarter of T), block 256 (thread = o).
__global__ __launch_bounds__(256) void k_out(const ushort_t* __restrict__ Y,
                                             const float* __restrict__ s2,
                                             const float* __restrict__ b2,
                                             const float* __restrict__ a0o,
                                             const float* __restrict__ a1o,
                                             const int* __restrict__ j1o,
                                             float* __restrict__ out){
    const int b = blockIdx.x;
    const int n = b >> 2, t0 = (b & 3) << 8, o = threadIdx.x;
    const float sc = s2[o], bs = b2[o], a0 = a0o[o], a1 = a1o[o];
    const int j1 = j1o[o];
    const ushort_t* yp = Y + (((size_t)n << 10) << 8) + o;
    float* op = out + (((size_t)n << 10) << 8) + o;
    float ym1 = (t0 > 0) ? bf2f(yp[(size_t)(t0 - 1) * 256]) : 0.f;
    float y0  = bf2f(yp[(size_t)t0 * 256]);
    #pragma unroll 4
    for (int t = t0; t < t0 + 256; ++t){
        float yp1 = (t < 1023) ? bf2f(yp[(size_t)(t + 1) * 256]) : 0.f;
        float zl = (j1 == 0) ? ym1 : y0;
        float zr = (j1 == 0) ? y0  : yp1;
        float z = a0 * zl + a1 * zr;
        op[(size_t)t * 256] = fmaf(z, sc, bs);
        ym1 = y0; y0 = yp1;
    }
}

extern "C" void kernel_launch(void* const* d_in, const int* in_sizes, int n_in,
                              void* d_out, int out_size, void* d_ws, size_t ws_size,
                              hipStream_t stream){
    const float* x    = (const float*)d_in[0];
    const float* g1   = (const float*)d_in[1];
    const float* be1  = (const float*)d_in[2];
    const float* sin_ = (const float*)d_in[3];
    const float* W    = (const float*)d_in[4];
    const float* cb   = (const float*)d_in[5];
    const float* sout = (const float*)d_in[6];
    const float* g2   = (const float*)d_in[7];
    const float* be2  = (const float*)d_in[8];
    float* out = (float*)d_out;

    char* ws = (char*)d_ws;
    ushort_t* Y  = (ushort_t*)ws;                       // 67108864 B (N*T*C bf16)
    ushort_t* WF = (ushort_t*)(ws + 67108864);          // 131072 B
    float* par = (float*)(ws + 67239936);
    float* s1  = par;          float* b1  = par + 256;
    float* a0i = par + 512;    float* a1i = par + 768;
    int*   i1i = (int*)(par + 1024);
    float* a0o = par + 1280;   float* a1o = par + 1536;
    int*   j1o = (int*)(par + 1792);
    float* s2  = par + 2048;   float* b2  = par + 2304;
    float* psum = par + 2560;            // 256*512
    float* psq  = psum + 131072;
    float* ZP   = psq  + 131072;
    float* ZQ   = ZP   + 131072;
    float* ZR   = ZQ   + 131072;
    float* B0p  = ZR   + 131072;         // 256*128 each
    float* B0q  = B0p  + 32768;
    float* BTp  = B0q  + 32768;
    float* BTq  = BTp  + 32768;

    k_stats1<<<512, 256, 0, stream>>>(x, psum, psq);
    k_fin1  <<<256, 256, 0, stream>>>(psum, psq, g1, be1, sin_, sout,
                                      s1, b1, a0i, a1i, i1i, a0o, a1o, j1o);
    k_wf    <<<32, 256, 0, stream>>>(W, WF);
    k_conv  <<<2048, 256, 0, stream>>>(x, WF, cb, s1, b1, a0i, a1i, i1i, Y);
    k_zstats<<<512, 256, 0, stream>>>(Y, ZP, ZQ, ZR, B0p, B0q, BTp, BTq);
    k_fin2  <<<256, 256, 0, stream>>>(ZP, ZQ, ZR, B0p, B0q, BTp, BTq,
                                      g2, be2, a0o, a1o, j1o, s2, b2);
    k_out   <<<512, 256, 0, stream>>>(Y, s2, b2, a0o, a1o, j1o, out);
}

// Round 2
// 151.178 us; speedup vs baseline: 1.4241x; 1.4241x over previous
//
#include <hip/hip_runtime.h>
#include <stddef.h>

typedef __attribute__((ext_vector_type(8))) short short8;
typedef __attribute__((ext_vector_type(4))) float f32x4;
typedef __attribute__((ext_vector_type(4))) int   i32x4;
typedef __attribute__((ext_vector_type(2))) unsigned int u32x2;
typedef unsigned short ushort_t;
typedef unsigned int uint_t;

#define NN 128
#define TT 1024
#define CC 256
#define NT 131072.0f   // N*T
#define EPS 1e-5f
#define LDE 260        // epilogue LDS stride (ushorts), multiple of 4

__device__ __forceinline__ float bf2f(ushort_t u){
    union { float f; uint_t i; } v; v.i = ((uint_t)u) << 16; return v.f;
}
__device__ __forceinline__ ushort_t f2bf(float f){
    union { float f; uint_t i; } v; v.f = f;
    uint_t r = v.i + 0x7fffu + ((v.i >> 16) & 1u);
    return (ushort_t)(r >> 16);
}
__device__ __forceinline__ uint_t pack2(float lo, float hi){
    return (uint_t)f2bf(lo) | ((uint_t)f2bf(hi) << 16);
}
__device__ __forceinline__ f32x4 ld4bf(const ushort_t* p){
    u32x2 u = *(const u32x2*)p;
    f32x4 r;
    r[0] = bf2f((ushort_t)(u[0] & 0xffffu));
    r[1] = bf2f((ushort_t)(u[0] >> 16));
    r[2] = bf2f((ushort_t)(u[1] & 0xffffu));
    r[3] = bf2f((ushort_t)(u[1] >> 16));
    return r;
}
__device__ __forceinline__ void wave_red(float& v){
    #pragma unroll
    for (int off = 32; off > 0; off >>= 1) v += __shfl_down(v, off);
}

// ---------------- Pass 1: per-channel stats of x (vectorized) ------------------
// grid 512, block 256. Block b: rows [b*256, b*256+256). Thread: 4 ch x 64 rows.
__global__ __launch_bounds__(256) void k_stats1(const float* __restrict__ x,
                                                float* __restrict__ psum,
                                                float* __restrict__ psq){
    __shared__ float ls[4][256], lq[4][256];
    const int b = blockIdx.x, tid = threadIdx.x;
    const int c4 = (tid & 63) << 2, rq = tid >> 6;
    const float* p = x + ((size_t)b << 16) + ((size_t)(rq * 64) << 8) + c4;
    f32x4 s = {0.f,0.f,0.f,0.f}, q = {0.f,0.f,0.f,0.f};
    #pragma unroll 8
    for (int k = 0; k < 64; ++k){
        f32x4 v = *(const f32x4*)&p[(size_t)k << 8];
        #pragma unroll
        for (int j = 0; j < 4; ++j){ s[j] += v[j]; q[j] = fmaf(v[j], v[j], q[j]); }
    }
    #pragma unroll
    for (int j = 0; j < 4; ++j){ ls[rq][c4 + j] = s[j]; lq[rq][c4 + j] = q[j]; }
    __syncthreads();
    const int c = tid;
    psum[c * 512 + b] = ls[0][c] + ls[1][c] + ls[2][c] + ls[3][c];
    psq [c * 512 + b] = lq[0][c] + lq[1][c] + lq[2][c] + lq[3][c];
}

// grid 256 (one per channel), block 256: reduce partials, emit BN1 affine + shift params.
__global__ __launch_bounds__(256) void k_fin1(const float* __restrict__ psum,
                                              const float* __restrict__ psq,
                                              const float* __restrict__ g1,
                                              const float* __restrict__ be1,
                                              const float* __restrict__ sin_,
                                              const float* __restrict__ sout,
                                              float* __restrict__ s1, float* __restrict__ b1,
                                              float* __restrict__ a0i, float* __restrict__ a1i,
                                              int* __restrict__ i1i,
                                              float* __restrict__ a0o, float* __restrict__ a1o,
                                              int* __restrict__ j1o){
    const int c = blockIdx.x, t = threadIdx.x;
    float s = psum[c * 512 + t] + psum[c * 512 + 256 + t];
    float q = psq [c * 512 + t] + psq [c * 512 + 256 + t];
    wave_red(s); wave_red(q);
    __shared__ float sm[8];
    const int wv = t >> 6, ln = t & 63;
    if (ln == 0){ sm[wv] = s; sm[4 + wv] = q; }
    __syncthreads();
    if (t == 0){
        float S = sm[0] + sm[1] + sm[2] + sm[3];
        float Q = sm[4] + sm[5] + sm[6] + sm[7];
        float mean = S / NT;
        float var  = Q / NT - mean * mean;
        float rstd = rsqrtf(var + EPS);
        float sc = rstd * g1[c];
        s1[c] = sc;
        b1[c] = be1[c] - mean * sc;
        float sv = sin_[c]; float fi = floorf(sv); float fr = sv - fi;
        a0i[c] = 1.f - fr; a1i[c] = fr; i1i[c] = (int)fi + 1;
        float so = sout[c]; float fo = floorf(so); float fro = so - fo;
        a0o[c] = 1.f - fro; a1o[c] = fro; j1o[c] = (int)fo + 1;
    }
}

// ---------------- W -> bf16 fragment-major layout ------------------------------
__global__ __launch_bounds__(256) void k_wf(const float* __restrict__ W, ushort_t* __restrict__ WF){
    const int gid = blockIdx.x * 256 + threadIdx.x;   // 8192 threads
    const int l = gid & 63, ob = (gid >> 6) & 15, ks = gid >> 10;
    const int row = ob * 16 + (l & 15);
    const int k0  = ks * 32 + (l >> 4) * 8;
    #pragma unroll
    for (int j = 0; j < 8; ++j)
        WF[(size_t)gid * 8 + j] = f2bf(W[(size_t)row * 256 + k0 + j]);
}

// B[g] = in-range ? fma(x[g], s, b) : 0   (per 4 channels)
__device__ __forceinline__ f32x4 bload(const float* xb, int g, f32x4 s, f32x4 b){
    f32x4 r = {0.f,0.f,0.f,0.f};
    if (g >= 0 && g < TT){
        f32x4 xv = *(const f32x4*)&xb[(size_t)g << 8];
        #pragma unroll
        for (int j = 0; j < 4; ++j) r[j] = fmaf(xv[j], s[j], b[j]);
    }
    return r;
}

// ---------------- Pass 2: fused BN1 + shift_in + conv + bias + relu -> Y bf16 (n,t,o)
// grid 2048 = (n, t-tile of 64), block 256 (4 waves).
__global__ __launch_bounds__(256) void k_conv(const float* __restrict__ x,
                                              const ushort_t* __restrict__ WF,
                                              const float* __restrict__ cb,
                                              const float* __restrict__ s1,
                                              const float* __restrict__ b1,
                                              const float* __restrict__ a0i,
                                              const float* __restrict__ a1i,
                                              const int* __restrict__ i1i,
                                              ushort_t* __restrict__ Y){
    __shared__ __align__(16) ushort_t lds[16640];
    const int tid = threadIdx.x;
    const int n  = blockIdx.x >> 4;
    const int t0 = (blockIdx.x & 15) << 6;
    const int lane = tid & 63, wv = tid >> 6;

    // ---- staging: thread = 4 channels x 16 consecutive t-rows, rolling regs ----
    {
        const int c4 = lane << 2;
        const f32x4 s1v = *(const f32x4*)&s1[c4];
        const f32x4 b1v = *(const f32x4*)&b1[c4];
        const f32x4 a0v = *(const f32x4*)&a0i[c4];
        const f32x4 a1v = *(const f32x4*)&a1i[c4];
        const i32x4 i1v = *(const i32x4*)&i1i[c4];
        const float* xb = x + ((size_t)n << 18) + c4;
        const int rt = t0 + (wv << 4);            // first global t this thread owns
        f32x4 Bm1 = bload(xb, rt - 1, s1v, b1v);
        f32x4 B0  = bload(xb, rt,     s1v, b1v);
        #pragma unroll 4
        for (int k = 0; k < 16; ++k){
            f32x4 Bp1 = bload(xb, rt + k + 1, s1v, b1v);
            f32x4 v;
            #pragma unroll
            for (int j = 0; j < 4; ++j){
                float zl = i1v[j] ? B0[j]  : Bm1[j];
                float zr = i1v[j] ? Bp1[j] : B0[j];
                v[j] = a0v[j] * zl + a1v[j] * zr;
            }
            const int tw = (wv << 4) + k;
            u32x2 w; w[0] = pack2(v[0], v[1]); w[1] = pack2(v[2], v[3]);
            *(u32x2*)&lds[(tw << 8) + (c4 ^ ((tw & 7) << 3))] = w;
            Bm1 = B0; B0 = Bp1;
        }
    }
    __syncthreads();

    // ---- MFMA: out tile 256(o) x 64(t), wave wv owns o in [wv*64, wv*64+64) ----
    const int l15 = lane & 15, lg = lane >> 4;
    f32x4 acc[4][4];
    #pragma unroll
    for (int r = 0; r < 4; ++r)
        #pragma unroll
        for (int q = 0; q < 4; ++q)
            acc[r][q] = (f32x4){0.f, 0.f, 0.f, 0.f};

    const short8* wf8 = (const short8*)WF;
    #pragma unroll
    for (int ks = 0; ks < 8; ++ks){
        short8 aF[4], bF[4];
        #pragma unroll
        for (int r = 0; r < 4; ++r)
            aF[r] = wf8[(ks * 16 + wv * 4 + r) * 64 + lane];
        const int kk = (ks << 5) + (lg << 3);
        #pragma unroll
        for (int q = 0; q < 4; ++q){
            const int t = (q << 4) | l15;
            bF[q] = *(const short8*)&lds[(t << 8) + (kk ^ ((t & 7) << 3))];
        }
        #pragma unroll
        for (int r = 0; r < 4; ++r)
            #pragma unroll
            for (int q = 0; q < 4; ++q)
                acc[r][q] = __builtin_amdgcn_mfma_f32_16x16x32_bf16(aF[r], bF[q], acc[r][q], 0, 0, 0);
    }
    __syncthreads();

    // ---- epilogue: bias + relu, transpose to [t][o] in LDS (stride LDE), b64 ----
    #pragma unroll
    for (int r = 0; r < 4; ++r){
        const int ob = (wv << 6) + (r << 4) + (lg << 2);
        const f32x4 cbv = *(const f32x4*)&cb[ob];
        #pragma unroll
        for (int q = 0; q < 4; ++q){
            const int t = (q << 4) | l15;
            float v[4];
            #pragma unroll
            for (int j = 0; j < 4; ++j){
                float z = acc[r][q][j] + cbv[j];
                v[j] = z > 0.f ? z : 0.f;
            }
            u32x2 w; w[0] = pack2(v[0], v[1]); w[1] = pack2(v[2], v[3]);
            *(u32x2*)&lds[t * LDE + ob] = w;
        }
    }
    __syncthreads();

    // ---- coalesced store: Y[(n*1024 + t0 + row)*256 + col4], dwordx2 ----
    u32x2* Yu = (u32x2*)Y;
    const size_t rbase = ((size_t)n << 10) + t0;
    #pragma unroll
    for (int it = 0; it < 16; ++it){
        const int row = (it << 2) + wv;
        u32x2 v = *(const u32x2*)&lds[row * LDE + (lane << 2)];
        Yu[((rbase + row) << 6) + lane] = v;
    }
}

// ---------------- Pass 3a: stats of shifted Y (P, Q, R, boundary terms) --------
// grid 512 = (n, quarter of T), block 256. Thread: 4 ch x 64 rows, rolling prev.
__global__ __launch_bounds__(256) void k_zstats(const ushort_t* __restrict__ Y,
                                                float* __restrict__ ZP, float* __restrict__ ZQ,
                                                float* __restrict__ ZR,
                                                float* __restrict__ B0p, float* __restrict__ B0q,
                                                float* __restrict__ BTp, float* __restrict__ BTq){
    __shared__ float lp[4][256], lq[4][256], lr[4][256];
    const int b = blockIdx.x, tid = threadIdx.x;
    const int n = b >> 2, o4 = (tid & 63) << 2, rq = tid >> 6;
    const int rs = ((b & 3) << 8) + (rq << 6);
    const ushort_t* yb = Y + ((size_t)n << 18) + o4;
    f32x4 P = {0.f,0.f,0.f,0.f}, Q = P, R = P;
    f32x4 prev = {0.f,0.f,0.f,0.f};
    if (rs > 0) prev = ld4bf(yb + ((size_t)(rs - 1) << 8));
    #pragma unroll 8
    for (int k = 0; k < 64; ++k){
        f32x4 y = ld4bf(yb + ((size_t)(rs + k) << 8));
        #pragma unroll
        for (int j = 0; j < 4; ++j){
            P[j] += y[j];
            Q[j] = fmaf(y[j], y[j], Q[j]);
            R[j] = fmaf(prev[j], y[j], R[j]);
        }
        prev = y;
    }
    #pragma unroll
    for (int j = 0; j < 4; ++j){
        lp[rq][o4 + j] = P[j]; lq[rq][o4 + j] = Q[j]; lr[rq][o4 + j] = R[j];
    }
    __syncthreads();
    const int o = tid;
    ZP[o * 512 + b] = lp[0][o] + lp[1][o] + lp[2][o] + lp[3][o];
    ZQ[o * 512 + b] = lq[0][o] + lq[1][o] + lq[2][o] + lq[3][o];
    ZR[o * 512 + b] = lr[0][o] + lr[1][o] + lr[2][o] + lr[3][o];
    if (((b & 3) == 0) && rq == 0){
        f32x4 y0 = ld4bf(yb);
        #pragma unroll
        for (int j = 0; j < 4; ++j){
            B0p[(o4 + j) * 128 + n] = y0[j];
            B0q[(o4 + j) * 128 + n] = y0[j] * y0[j];
        }
    }
    if (((b & 3) == 3) && rq == 3){
        f32x4 yT = ld4bf(yb + ((size_t)1023 << 8));
        #pragma unroll
        for (int j = 0; j < 4; ++j){
            BTp[(o4 + j) * 128 + n] = yT[j];
            BTq[(o4 + j) * 128 + n] = yT[j] * yT[j];
        }
    }
}

// grid 256 (one per o), block 256: reduce + assemble shifted stats -> BN2 affine.
__global__ __launch_bounds__(256) void k_fin2(const float* __restrict__ ZP,
                                              const float* __restrict__ ZQ,
                                              const float* __restrict__ ZR,
                                              const float* __restrict__ B0p,
                                              const float* __restrict__ B0q,
                                              const float* __restrict__ BTp,
                                              const float* __restrict__ BTq,
                                              const float* __restrict__ g2,
                                              const float* __restrict__ be2,
                                              const float* __restrict__ a0o,
                                              const float* __restrict__ a1o,
                                              const int* __restrict__ j1o,
                                              float* __restrict__ s2, float* __restrict__ b2){
    const int o = blockIdx.x, t = threadIdx.x;
    float P = ZP[o * 512 + t] + ZP[o * 512 + 256 + t];
    float Q = ZQ[o * 512 + t] + ZQ[o * 512 + 256 + t];
    float R = ZR[o * 512 + t] + ZR[o * 512 + 256 + t];
    float b0 = 0.f, b0s = 0.f, btv = 0.f, bts = 0.f;
    if (t < 128){
        b0 = B0p[o * 128 + t]; b0s = B0q[o * 128 + t];
        btv = BTp[o * 128 + t]; bts = BTq[o * 128 + t];
    }
    wave_red(P); wave_red(Q); wave_red(R);
    wave_red(b0); wave_red(b0s); wave_red(btv); wave_red(bts);
    __shared__ float sm[4][7];
    const int wv = t >> 6, ln = t & 63;
    if (ln == 0){
        sm[wv][0] = P; sm[wv][1] = Q; sm[wv][2] = R;
        sm[wv][3] = b0; sm[wv][4] = b0s; sm[wv][5] = btv; sm[wv][6] = bts;
    }
    __syncthreads();
    if (t == 0){
        float v[7];
        #pragma unroll
        for (int k = 0; k < 7; ++k)
            v[k] = sm[0][k] + sm[1][k] + sm[2][k] + sm[3][k];
        const float a0 = a0o[o], a1 = a1o[o];
        const int j1 = j1o[o];
        float sz, sq;
        if (j1 == 0){   // Z[t] = a0*Y[t-1](t>=1) + a1*Y[t]
            sz = a0 * (v[0] - v[5]) + a1 * v[0];
            sq = a0 * a0 * (v[1] - v[6]) + a1 * a1 * v[1] + 2.f * a0 * a1 * v[2];
        } else {        // Z[t] = a0*Y[t] + a1*Y[t+1](t<=T-2)
            sz = a0 * v[0] + a1 * (v[0] - v[3]);
            sq = a0 * a0 * v[1] + a1 * a1 * (v[1] - v[4]) + 2.f * a0 * a1 * v[2];
        }
        float mean = sz / NT;
        float var  = sq / NT - mean * mean;
        float rstd = rsqrtf(var + EPS);
        float sc = rstd * g2[o];
        s2[o] = sc;
        b2[o] = be2[o] - mean * sc;
    }
}

// ---------------- Pass 3b: shift_out + BN2 + write fp32 output (n,t,o) ---------
// grid 512 = (n, quarter of T), block 256. Thread: 4 ch x 64 rows, rolling regs.
__global__ __launch_bounds__(256) void k_out(const ushort_t* __restrict__ Y,
                                             const float* __restrict__ s2,
                                             const float* __restrict__ b2,
                                             const float* __restrict__ a0o,
                                             const float* __restrict__ a1o,
                                             const int* __restrict__ j1o,
                                             float* __restrict__ out){
    const int b = blockIdx.x, tid = threadIdx.x;
    const int n = b >> 2, o4 = (tid & 63) << 2, rq = tid >> 6;
    const int rs = ((b & 3) << 8) + (rq << 6);
    const f32x4 sc = *(const f32x4*)&s2[o4];
    const f32x4 bs = *(const f32x4*)&b2[o4];
    const f32x4 a0 = *(const f32x4*)&a0o[o4];
    const f32x4 a1 = *(const f32x4*)&a1o[o4];
    const i32x4 j1 = *(const i32x4*)&j1o[o4];
    const ushort_t* yb = Y + ((size_t)n << 18) + o4;
    float* ob = out + ((size_t)n << 18) + o4;
    f32x4 ym1 = {0.f,0.f,0.f,0.f};
    if (rs > 0) ym1 = ld4bf(yb + ((size_t)(rs - 1) << 8));
    f32x4 y0 = ld4bf(yb + ((size_t)rs << 8));
    #pragma unroll 8
    for (int k = 0; k < 64; ++k){
        const int t = rs + k;
        f32x4 yp1 = {0.f,0.f,0.f,0.f};
        if (t < 1023) yp1 = ld4bf(yb + ((size_t)(t + 1) << 8));
        f32x4 ov;
        #pragma unroll
        for (int j = 0; j < 4; ++j){
            float zl = j1[j] ? y0[j]  : ym1[j];
            float zr = j1[j] ? yp1[j] : y0[j];
            float z = a0[j] * zl + a1[j] * zr;
            ov[j] = fmaf(z, sc[j], bs[j]);
        }
        *(f32x4*)&ob[(size_t)t << 8] = ov;
        ym1 = y0; y0 = yp1;
    }
}

extern "C" void kernel_launch(void* const* d_in, const int* in_sizes, int n_in,
                              void* d_out, int out_size, void* d_ws, size_t ws_size,
                              hipStream_t stream){
    const float* x    = (const float*)d_in[0];
    const float* g1   = (const float*)d_in[1];
    const float* be1  = (const float*)d_in[2];
    const float* sin_ = (const float*)d_in[3];
    const float* W    = (const float*)d_in[4];
    const float* cb   = (const float*)d_in[5];
    const float* sout = (const float*)d_in[6];
    const float* g2   = (const float*)d_in[7];
    const float* be2  = (const float*)d_in[8];
    float* out = (float*)d_out;

    char* ws = (char*)d_ws;
    ushort_t* Y  = (ushort_t*)ws;                       // 67108864 B (N*T*C bf16)
    ushort_t* WF = (ushort_t*)(ws + 67108864);          // 131072 B
    float* par = (float*)(ws + 67239936);
    float* s1  = par;          float* b1  = par + 256;
    float* a0i = par + 512;    float* a1i = par + 768;
    int*   i1i = (int*)(par + 1024);
    float* a0o = par + 1280;   float* a1o = par + 1536;
    int*   j1o = (int*)(par + 1792);
    float* s2  = par + 2048;   float* b2  = par + 2304;
    float* psum = par + 2560;            // 256*512
    float* psq  = psum + 131072;
    float* ZP   = psq  + 131072;
    float* ZQ   = ZP   + 131072;
    float* ZR   = ZQ   + 131072;
    float* B0p  = ZR   + 131072;         // 256*128 each
    float* B0q  = B0p  + 32768;
    float* BTp  = B0q  + 32768;
    float* BTq  = BTp  + 32768;

    k_stats1<<<512, 256, 0, stream>>>(x, psum, psq);
    k_fin1  <<<256, 256, 0, stream>>>(psum, psq, g1, be1, sin_, sout,
                                      s1, b1, a0i, a1i, i1i, a0o, a1o, j1o);
    k_wf    <<<32, 256, 0, stream>>>(W, WF);
    k_conv  <<<2048, 256, 0, stream>>>(x, WF, cb, s1, b1, a0i, a1i, i1i, Y);
    k_zstats<<<512, 256, 0, stream>>>(Y, ZP, ZQ, ZR, B0p, B0q, BTp, BTq);
    k_fin2  <<<256, 256, 0, stream>>>(ZP, ZQ, ZR, B0p, B0q, BTp, BTq,
                                      g2, be2, a0o, a1o, j1o, s2, b2);
    k_out   <<<512, 256, 0, stream>>>(Y, s2, b2, a0o, a1o, j1o, out);
}